// Round 1
// 372.075 us; speedup vs baseline: 1.1822x; 1.1822x over previous
//
#include <hip/hip_runtime.h>
#include <stdint.h>

#define BB 128
#define WW 512
#define HH 512
#define TILE 128
#define BK 64

typedef __attribute__((ext_vector_type(8))) short bf16x8;
typedef __attribute__((ext_vector_type(4))) float f32x4;

__device__ __forceinline__ float bf2f(unsigned short u) {
  union { unsigned int i; float f; } v;
  v.i = ((unsigned int)u) << 16;
  return v.f;
}
// pack two f32 into two bf16 (bit-truncation; |rel err| <= 2^-8, fine vs 6.1e-2 thr)
__device__ __forceinline__ unsigned int pack_bf2(float lo, float hi) {
  union { float f; unsigned int u; } a, b;
  a.f = lo; b.f = hi;
  return (a.u >> 16) | (b.u & 0xFFFF0000u);
}
__device__ __forceinline__ float dot4f(float4 u, const float* gp) {
  return u.x * gp[0] + u.y * gp[1] + u.z * gp[2] + u.w * gp[3];
}
__device__ __forceinline__ void gload_lds16(const void* src, void* lds_dst) {
  __builtin_amdgcn_global_load_lds(
      (const __attribute__((address_space(1))) unsigned int*)src,
      (__attribute__((address_space(3))) unsigned int*)lds_dst, 16, 0, 0);
}

// -------- K01: blocks 0..11: [gw | gfo] = g @ [w_w ; W_w].T  (MFMA, M=128,N=1536,K=512)
//          blocks 12..75: u_w -> pre-swizzled bf16 image u_wb for k2's global_load_lds
// u_wb layout: [kt][row][e] (kt 0..7, row 0..511, e 0..63 bf16), where element e of
// row holds u_w[row][kt*64 + (e ^ ((row&7)<<3))]  (XOR swizzle -> conflict-free ds_read_b128)
__global__ __launch_bounds__(256) void k01(
    const float* __restrict__ g, const float* __restrict__ W_w,
    const float* __restrict__ w_w, const float* __restrict__ u_w,
    float* __restrict__ gw, float* __restrict__ gfo,
    unsigned short* __restrict__ u_wb) {
  __shared__ __align__(16) unsigned short As[TILE * BK];
  __shared__ __align__(16) unsigned short Bs[TILE * BK];
  const int bid = blockIdx.x;
  const int t = threadIdx.x;

  if (bid >= 12) {
    // ---- u_w convert: 32768 16B-chunks total, 2 per thread over 64 blocks
    const int cid0 = (bid - 12) * 256 + t;
    for (int idx = cid0; idx < 32768; idx += 16384) {
      const int kt  = idx >> 12;       // 4096 chunks per kt
      const int rem = idx & 4095;
      const int r   = rem >> 3;        // row 0..511
      const int e   = (rem & 7) * 8;   // element group 0,8,..,56
      const int c0  = kt * 64 + (e ^ ((r & 7) << 3));
      const float4* sp = (const float4*)(u_w + (size_t)r * HH + c0);
      float4 s0 = sp[0], s1 = sp[1];
      uint4 pv;
      pv.x = pack_bf2(s0.x, s0.y); pv.y = pack_bf2(s0.z, s0.w);
      pv.z = pack_bf2(s1.x, s1.y); pv.w = pack_bf2(s1.z, s1.w);
      *(uint4*)(u_wb + (size_t)idx * 8) = pv;
    }
    return;
  }

  // ---- original k1 MFMA GEMM (unchanged, verified)
  const int nc = bid;
  const int lane = t & 63, wave = t >> 6;
  const int wm = wave >> 1, wn = wave & 1;
  const int l15 = lane & 15, quad = lane >> 4;

  const float* wsrc = (nc < 4) ? (w_w + (size_t)nc * TILE * HH)
                               : (W_w + (size_t)(nc - 4) * TILE * HH);

  const f32x4 zero = {0.f, 0.f, 0.f, 0.f};
  f32x4 acc[4][4];
#pragma unroll
  for (int i = 0; i < 4; ++i)
#pragma unroll
    for (int j = 0; j < 4; ++j) acc[i][j] = zero;

  const int srow = t >> 3;
  const int scol = (t & 7) * 8;

  for (int kt = 0; kt < 8; ++kt) {
    const int k0 = kt * BK;
#pragma unroll
    for (int p = 0; p < 4; ++p) {
      const int row = p * 32 + srow;
      const float4* ap = (const float4*)(g    + (size_t)row * HH + k0 + scol);
      const float4* bp = (const float4*)(wsrc + (size_t)row * HH + k0 + scol);
      float4 a0 = ap[0], a1 = ap[1], b0 = bp[0], b1 = bp[1];
      uint4 av, bv;
      av.x = pack_bf2(a0.x, a0.y); av.y = pack_bf2(a0.z, a0.w);
      av.z = pack_bf2(a1.x, a1.y); av.w = pack_bf2(a1.z, a1.w);
      bv.x = pack_bf2(b0.x, b0.y); bv.y = pack_bf2(b0.z, b0.w);
      bv.z = pack_bf2(b1.x, b1.y); bv.w = pack_bf2(b1.z, b1.w);
      *(uint4*)(As + row * BK + scol) = av;
      *(uint4*)(Bs + row * BK + scol) = bv;
    }
    __syncthreads();
#pragma unroll
    for (int ks = 0; ks < 2; ++ks) {
      bf16x8 af[4], bg[4];
#pragma unroll
      for (int i = 0; i < 4; ++i)
        af[i] = *(const bf16x8*)(As + (wm * 64 + i * 16 + l15) * BK + ks * 32 + quad * 8);
#pragma unroll
      for (int j = 0; j < 4; ++j)
        bg[j] = *(const bf16x8*)(Bs + (wn * 64 + j * 16 + l15) * BK + ks * 32 + quad * 8);
#pragma unroll
      for (int i = 0; i < 4; ++i)
#pragma unroll
        for (int j = 0; j < 4; ++j)
          acc[i][j] = __builtin_amdgcn_mfma_f32_16x16x32_bf16(af[i], bg[j], acc[i][j], 0, 0, 0);
    }
    __syncthreads();
  }

#pragma unroll
  for (int j = 0; j < 4; ++j) {
    const int nl = wn * 64 + j * 16 + l15;
#pragma unroll
    for (int i = 0; i < 4; ++i) {
#pragma unroll
      for (int r = 0; r < 4; ++r) {
        const int b = wm * 64 + i * 16 + quad * 4 + r;
        const float v = acc[i][j][r];
        if (nc < 4) gw[(size_t)b * HH + nc * TILE + nl] = v;
        else        gfo[(size_t)b * 2 * HH + (nc - 4) * TILE + nl] = v;
      }
    }
  }
}

// -------- K2: full-N fused block. grid 512 = (b, wc); 512 thr = 8 waves (2M x 4N).
// Per block: Z[128w x 512n] = h_tile @ u_w.T, fused exp(sigmoid) softmax partials,
// h column sums. h read EXACTLY ONCE device-wide; B staged async from pre-swizzled u_wb.
__global__ __launch_bounds__(512, 2) void k2_fused(
    const float* __restrict__ h, const float* __restrict__ c,
    const unsigned short* __restrict__ u_wb, const float* __restrict__ u_b,
    const float* __restrict__ gw,
    float* __restrict__ hsumP, float* __restrict__ denP, float* __restrict__ numP) {
  __shared__ __align__(16) unsigned short Bs[512 * 64];   // 64 KB (swizzled image)
  __shared__ __align__(16) unsigned short As[128 * 64];   // 16 KB (swizzled)
  __shared__ float colred[8][64];                          // 2 KB
  __shared__ float redD[2][512];                           // 4 KB
  __shared__ float redN[2][512];                           // 4 KB

  const int bid = blockIdx.x;
  const int b = bid >> 2, wc = bid & 3;
  const int t = threadIdx.x;
  const int lane = t & 63, wave = t >> 6;
  const int wm = wave >> 2, wn = wave & 3;     // 2 x 4 wave grid
  const int l15 = lane & 15, quad = lane >> 4;

  const size_t hbase = ((size_t)b * WW + (size_t)wc * 128) * HH;

  const f32x4 zero = {0.f, 0.f, 0.f, 0.f};
  f32x4 acc[4][8];
#pragma unroll
  for (int i = 0; i < 4; ++i)
#pragma unroll
    for (int j = 0; j < 8; ++j) acc[i][j] = zero;

  const int srow = t >> 3;          // 0..63
  const int scol = (t & 7) * 8;     // 0..56

  for (int kt = 0; kt < 8; ++kt) {
    const int k0 = kt * 64;

    // flush previous kt's column sums (colred ordered by end-of-kt barrier)
    if (kt > 0 && t < 64) {
      float tot = 0.f;
#pragma unroll
      for (int gq = 0; gq < 8; ++gq) tot += colred[gq][t];
      hsumP[((size_t)b * 4 + wc) * HH + (kt - 1) * 64 + t] = tot;
    }

    // B: async global->LDS, linear copy of pre-swizzled 64KB chunk (8 issues/wave)
#pragma unroll
    for (int it = 0; it < 8; ++it) {
      const int s = wave * 8 + it;                 // 1KB segment id (wave-uniform)
      const unsigned short* src =
          u_wb + ((size_t)kt * 32768 + (size_t)s * 512 + (size_t)lane * 8);
      gload_lds16(src, Bs + (size_t)s * 512);
    }

    // A: h f32 -> bf16 reg-staged, XOR-swizzled LDS write
#pragma unroll
    for (int p = 0; p < 2; ++p) {
      const int row = p * 64 + srow;
      const float4* ap = (const float4*)(h + hbase + (size_t)row * HH + k0 + scol);
      float4 a0 = ap[0], a1 = ap[1];
      uint4 av;
      av.x = pack_bf2(a0.x, a0.y); av.y = pack_bf2(a0.z, a0.w);
      av.z = pack_bf2(a1.x, a1.y); av.w = pack_bf2(a1.z, a1.w);
      *(uint4*)(As + row * 64 + (scol ^ ((row & 7) << 3))) = av;
    }
    __syncthreads();

    // column sums of current A tile (for h_avg), swizzle-aware reads
    {
      const int col = t & 63, gq = t >> 6;
      float s = 0.f;
#pragma unroll
      for (int rr = 0; rr < 16; ++rr) {
        const int row = gq * 16 + rr;
        s += bf2f(As[row * 64 + (col ^ ((row & 7) << 3))]);
      }
      colred[gq][col] = s;
    }

    // MFMA
#pragma unroll
    for (int ks = 0; ks < 2; ++ks) {
      bf16x8 af[4], bg[8];
#pragma unroll
      for (int i = 0; i < 4; ++i) {
        const int row = wm * 64 + i * 16 + l15;
        af[i] = *(const bf16x8*)(As + row * 64 + ((ks * 32 + quad * 8) ^ ((row & 7) << 3)));
      }
#pragma unroll
      for (int j = 0; j < 8; ++j) {
        const int row = wn * 128 + j * 16 + l15;
        bg[j] = *(const bf16x8*)(Bs + row * 64 + ((ks * 32 + quad * 8) ^ ((row & 7) << 3)));
      }
#pragma unroll
      for (int i = 0; i < 4; ++i)
#pragma unroll
        for (int j = 0; j < 8; ++j)
          acc[i][j] = __builtin_amdgcn_mfma_f32_16x16x32_bf16(af[i], bg[j], acc[i][j], 0, 0, 0);
    }
    __syncthreads();
  }

  // flush last kt's column sums
  if (t < 64) {
    float tot = 0.f;
#pragma unroll
    for (int gq = 0; gq < 8; ++gq) tot += colred[gq][t];
    hsumP[((size_t)b * 4 + wc) * HH + 7 * 64 + t] = tot;
  }

  // Epilogue: e = exp(sigmoid(Z + gw + u_b)); reduce over this block's 128 w's.
#pragma unroll
  for (int j = 0; j < 8; ++j) {
    const int n = wn * 128 + j * 16 + l15;
    const float gwub = gw[(size_t)b * HH + n] + u_b[n];
    float dsum = 0.f, nsum = 0.f;
#pragma unroll
    for (int i = 0; i < 4; ++i) {
#pragma unroll
      for (int r = 0; r < 4; ++r) {
        const int m = wm * 64 + i * 16 + quad * 4 + r;
        const float z = acc[i][j][r] + gwub;
        const float sig = 1.f / (1.f + __expf(-z));
        const float e = __expf(sig);
        dsum += e;
        nsum += e * c[hbase + (size_t)m * HH + n];
      }
    }
    dsum += __shfl_xor(dsum, 16);
    dsum += __shfl_xor(dsum, 32);
    nsum += __shfl_xor(nsum, 16);
    nsum += __shfl_xor(nsum, 32);
    if (quad == 0) { redD[wm][n] = dsum; redN[wm][n] = nsum; }
  }
  __syncthreads();
  {
    const size_t o = ((size_t)b * 4 + wc) * HH + t;
    denP[o] = redD[0][t] + redD[1][t];
    numP[o] = redN[0][t] + redN[1][t];
  }
}

// -------- K3: fo gates + final outputs. grid 512 = (b, q); 1 dot per thread.
__global__ __launch_bounds__(256) void k3_final(
    const float* __restrict__ c_g, const float* __restrict__ U_w,
    const float* __restrict__ U_b,
    const float* __restrict__ gfo, const float* __restrict__ hsumP,
    const float* __restrict__ denP, const float* __restrict__ numP,
    float* __restrict__ out) {
  __shared__ __align__(16) float ha[HH];
  __shared__ float ncL[128];
  __shared__ float oL[128];
  const int bid = blockIdx.x;
  const int b = bid >> 2, q = bid & 3;
  const int t = threadIdx.x;

  for (int i = t; i < HH; i += 256) {
    const float* hp = hsumP + (size_t)b * 4 * HH + i;
    ha[i] = (hp[0] + hp[HH] + hp[2 * HH] + hp[3 * HH]) * (1.f / (float)WW);
  }
  __syncthreads();

  const int isF = (t < 128);
  const int n = q * 128 + (t & 127);
  const int row = isF ? n : (HH + n);
  const float4* up = (const float4*)(U_w + (size_t)row * HH);

  float p0 = 0.f, p1 = 0.f, p2 = 0.f, p3 = 0.f;
#pragma unroll 4
  for (int k4 = 0; k4 < 128; k4 += 4) {
    p0 += dot4f(up[k4 + 0], ha + k4 * 4 + 0);
    p1 += dot4f(up[k4 + 1], ha + k4 * 4 + 4);
    p2 += dot4f(up[k4 + 2], ha + k4 * 4 + 8);
    p3 += dot4f(up[k4 + 3], ha + k4 * 4 + 12);
  }
  const float dot = (p0 + p1) + (p2 + p3);
  const float logit = gfo[(size_t)b * 2 * HH + row] + dot + U_b[row];
  const float sg = 1.f / (1.f + __expf(-logit));

  if (isF) {
    const float* dp = denP + (size_t)b * 4 * HH + n;
    const float* np = numP + (size_t)b * 4 * HH + n;
    const float den = dp[0] + dp[HH] + dp[2 * HH] + dp[3 * HH];
    const float num = np[0] + np[HH] + np[2 * HH] + np[3 * HH];
    const float ncv = sg * c_g[(size_t)b * HH + n] + num / den;
    ncL[t] = ncv;
    out[(size_t)BB * HH + (size_t)b * HH + n] = ncv;     // new_c
  } else {
    oL[t - 128] = sg;
  }
  __syncthreads();
  if (isF) {
    out[(size_t)b * HH + n] = oL[t] * tanhf(ncL[t]);     // new_g
  }
}

extern "C" void kernel_launch(void* const* d_in, const int* in_sizes, int n_in,
                              void* d_out, int out_size, void* d_ws, size_t ws_size,
                              hipStream_t stream) {
  const float* g   = (const float*)d_in[0];
  const float* c_g = (const float*)d_in[1];
  const float* h   = (const float*)d_in[2];
  const float* c   = (const float*)d_in[3];
  const float* W_w = (const float*)d_in[4];
  const float* w_w = (const float*)d_in[5];
  const float* U_w = (const float*)d_in[6];
  const float* U_b = (const float*)d_in[7];
  const float* u_w = (const float*)d_in[8];
  const float* u_b = (const float*)d_in[9];

  float* ws    = (float*)d_ws;
  float* gw    = ws;                         // B*H
  float* gfo   = gw + BB * HH;               // B*2H
  float* hsumP = gfo + (size_t)BB * 2 * HH;  // B*4*H
  float* denP  = hsumP + (size_t)BB * 4 * HH;
  float* numP  = denP + (size_t)BB * 4 * HH;
  unsigned short* u_wb = (unsigned short*)(numP + (size_t)BB * 4 * HH);  // 512 KB
  float* out = (float*)d_out;

  hipLaunchKernelGGL(k01, dim3(76), dim3(256), 0, stream, g, W_w, w_w, u_w, gw, gfo, u_wb);
  hipLaunchKernelGGL(k2_fused, dim3(512), dim3(512), 0, stream,
                     h, c, u_wb, u_b, gw, hsumP, denP, numP);
  hipLaunchKernelGGL(k3_final, dim3(512), dim3(256), 0, stream,
                     c_g, U_w, U_b, gfo, hsumP, denP, numP, out);
}